// Round 2
// baseline (283.769 us; speedup 1.0000x reference)
//
#include <hip/hip_runtime.h>

#define HID 15

// ---- prepared weight buffer layout (float offsets in d_ws) ----
constexpr int OFF_YW0 = 0;       // 120  softplus'ed
constexpr int OFF_YWS = 120;     // 675  softplus'ed
constexpr int OFF_ZW0 = 795;     // 120
constexpr int OFF_ZWS = 915;     // 675
constexpr int OFF_TW0 = 1590;    // 60   softplus'ed
constexpr int OFF_TWS = 1650;    // 675  softplus'ed
constexpr int OFF_X0W = 2325;    // 240
constexpr int OFF_Y0W = 2565;    // 120  softplus'ed
constexpr int OFF_Z0W = 2685;    // 120
constexpr int OFF_T0W = 2805;    // 60   softplus'ed
constexpr int OFF_XWS = 2865;    // 675  softplus'ed
constexpr int OFF_XSW = 3540;    // 720
constexpr int OFF_XYW = 4260;    // 675  softplus'ed
constexpr int OFF_XZW = 4935;    // 675
constexpr int OFF_XTW = 5610;    // 675  softplus'ed
constexpr int OFF_FW  = 6285;    // 225
constexpr int OFF_YB  = 6510;    // 60  (yb, all 4 layers)
constexpr int OFF_ZB  = 6570;    // 60
constexpr int OFF_TB  = 6630;    // 60
constexpr int OFF_XFB = 6690;    // 15  (x0b + y0b + z0b + t0b)
constexpr int OFF_XLB = 6705;    // 45  (xb + xsb + xyb + xzb + xtb, per iter)
constexpr int OFF_FB  = 6750;    // 15
constexpr int W_TOTAL = 6765;

__device__ __forceinline__ float sp_stable(float v) {
  // softplus(v) = max(v,0) + log1p(exp(-|v|)); e in (0,1] so __logf(1+e) is accurate
  float ax = __builtin_fabsf(v);
  float e  = __expf(-ax);
  return fmaxf(v, 0.0f) + __logf(1.0f + e);
}

__device__ __forceinline__ float sigmoid_f(float v) {
  return __builtin_amdgcn_rcpf(1.0f + __expf(-v));
}

// ---------------- weight preparation (runs once per launch, trivial cost) ---------
__global__ void prep_kernel(
    const float* __restrict__ yW0, const float* __restrict__ yWs, const float* __restrict__ yb,
    const float* __restrict__ zW0, const float* __restrict__ zWs, const float* __restrict__ zb,
    const float* __restrict__ tW0, const float* __restrict__ tWs, const float* __restrict__ tb,
    const float* __restrict__ x0W, const float* __restrict__ x0b,
    const float* __restrict__ y0W, const float* __restrict__ y0b,
    const float* __restrict__ z0W, const float* __restrict__ z0b,
    const float* __restrict__ t0W, const float* __restrict__ t0b,
    const float* __restrict__ xWs, const float* __restrict__ xb,
    const float* __restrict__ xsW, const float* __restrict__ xsb,
    const float* __restrict__ xyW, const float* __restrict__ xyb,
    const float* __restrict__ xzW, const float* __restrict__ xzb,
    const float* __restrict__ xtW, const float* __restrict__ xtb,
    const float* __restrict__ fW, const float* __restrict__ fb,
    float* __restrict__ w)
{
  const int tid = blockIdx.x * blockDim.x + threadIdx.x;
  const int str = gridDim.x * blockDim.x;
  for (int i = tid; i < 120; i += str) w[OFF_YW0 + i] = sp_stable(yW0[i]);
  for (int i = tid; i < 675; i += str) w[OFF_YWS + i] = sp_stable(yWs[i]);
  for (int i = tid; i < 120; i += str) w[OFF_ZW0 + i] = zW0[i];
  for (int i = tid; i < 675; i += str) w[OFF_ZWS + i] = zWs[i];
  for (int i = tid; i <  60; i += str) w[OFF_TW0 + i] = sp_stable(tW0[i]);
  for (int i = tid; i < 675; i += str) w[OFF_TWS + i] = sp_stable(tWs[i]);
  for (int i = tid; i < 240; i += str) w[OFF_X0W + i] = x0W[i];
  for (int i = tid; i < 120; i += str) w[OFF_Y0W + i] = sp_stable(y0W[i]);
  for (int i = tid; i < 120; i += str) w[OFF_Z0W + i] = z0W[i];
  for (int i = tid; i <  60; i += str) w[OFF_T0W + i] = sp_stable(t0W[i]);
  for (int i = tid; i < 675; i += str) w[OFF_XWS + i] = sp_stable(xWs[i]);
  for (int i = tid; i < 720; i += str) w[OFF_XSW + i] = xsW[i];
  for (int i = tid; i < 675; i += str) w[OFF_XYW + i] = sp_stable(xyW[i]);
  for (int i = tid; i < 675; i += str) w[OFF_XZW + i] = xzW[i];
  for (int i = tid; i < 675; i += str) w[OFF_XTW + i] = sp_stable(xtW[i]);
  for (int i = tid; i < 225; i += str) w[OFF_FW  + i] = fW[i];
  for (int i = tid; i <  60; i += str) w[OFF_YB  + i] = yb[i];
  for (int i = tid; i <  60; i += str) w[OFF_ZB  + i] = zb[i];
  for (int i = tid; i <  60; i += str) w[OFF_TB  + i] = tb[i];
  for (int i = tid; i <  15; i += str) w[OFF_XFB + i] = x0b[i] + y0b[i] + z0b[i] + t0b[i];
  for (int i = tid; i <  45; i += str) w[OFF_XLB + i] = xb[i] + xsb[i] + xyb[i] + xzb[i] + xtb[i];
  for (int i = tid; i <  15; i += str) w[OFF_FB  + i] = fb[i];
}

// ---------------- main forward kernel: one thread per row --------------------------
// k-OUTER / j-INNER: 15 independent accumulator chains; dep distance 15 instrs
// (~30 cyc) >> 4-cyc FMA latency -> latency fully hidden within a single wave.
template<int IN>
__device__ __forceinline__ void matvec(const float* __restrict__ W,
                                       const float* __restrict__ b,
                                       const float* __restrict__ in,
                                       float* __restrict__ acc) {
#pragma unroll
  for (int j = 0; j < HID; ++j) acc[j] = b[j];
#pragma unroll
  for (int k = 0; k < IN; ++k) {
#pragma unroll
    for (int j = 0; j < HID; ++j) acc[j] = fmaf(in[k], W[j * IN + k], acc[j]);
  }
}

template<int IN>
__device__ __forceinline__ void matvec_acc(const float* __restrict__ W,
                                           const float* __restrict__ in,
                                           float* __restrict__ acc) {
#pragma unroll
  for (int k = 0; k < IN; ++k) {
#pragma unroll
    for (int j = 0; j < HID; ++j) acc[j] = fmaf(in[k], W[j * IN + k], acc[j]);
  }
}

__global__ __launch_bounds__(256, 2) void isnn_fwd(
    const float* __restrict__ x0g, const float* __restrict__ y0g,
    const float* __restrict__ z0g, const float* __restrict__ t0g,
    const float* __restrict__ w,   float* __restrict__ outg, int n)
{
  const int r = blockIdx.x * blockDim.x + threadIdx.x;
  if (r >= n) return;

  float x0v[16], y0v[8], z0v[8], t0v[4];
#pragma unroll
  for (int k = 0; k < 4; ++k)
    ((float4*)x0v)[k] = ((const float4*)(x0g))[(size_t)r * 4 + k];
#pragma unroll
  for (int k = 0; k < 2; ++k)
    ((float4*)y0v)[k] = ((const float4*)(y0g))[(size_t)r * 2 + k];
#pragma unroll
  for (int k = 0; k < 2; ++k)
    ((float4*)z0v)[k] = ((const float4*)(z0g))[(size_t)r * 2 + k];
  ((float4*)t0v)[0] = ((const float4*)(t0g))[(size_t)r];

  float y[HID], z[HID], t[HID], x[HID], a[HID];

  // ---- y tower: softplus activations, softplus'ed weights
  matvec<8>(w + OFF_YW0, w + OFF_YB, y0v, a);
#pragma unroll
  for (int j = 0; j < HID; ++j) y[j] = sp_stable(a[j]);
  for (int i = 0; i < 3; ++i) {
    matvec<15>(w + OFF_YWS + i * 225, w + OFF_YB + 15 + i * 15, y, a);
#pragma unroll
    for (int j = 0; j < HID; ++j) y[j] = sp_stable(a[j]);
  }

  // ---- z tower: sigmoid activations, plain weights
  matvec<8>(w + OFF_ZW0, w + OFF_ZB, z0v, a);
#pragma unroll
  for (int j = 0; j < HID; ++j) z[j] = sigmoid_f(a[j]);
  for (int i = 0; i < 3; ++i) {
    matvec<15>(w + OFF_ZWS + i * 225, w + OFF_ZB + 15 + i * 15, z, a);
#pragma unroll
    for (int j = 0; j < HID; ++j) z[j] = sigmoid_f(a[j]);
  }

  // ---- t tower: sigmoid activations, softplus'ed weights
  matvec<4>(w + OFF_TW0, w + OFF_TB, t0v, a);
#pragma unroll
  for (int j = 0; j < HID; ++j) t[j] = sigmoid_f(a[j]);
  for (int i = 0; i < 3; ++i) {
    matvec<15>(w + OFF_TWS + i * 225, w + OFF_TB + 15 + i * 15, t, a);
#pragma unroll
    for (int j = 0; j < HID; ++j) t[j] = sigmoid_f(a[j]);
  }

  // ---- x path: first 4-branch block
  matvec<16>(w + OFF_X0W, w + OFF_XFB, x0v, a);
  matvec_acc<8>(w + OFF_Y0W, y0v, a);
  matvec_acc<8>(w + OFF_Z0W, z0v, a);
  matvec_acc<4>(w + OFF_T0W, t0v, a);
#pragma unroll
  for (int j = 0; j < HID; ++j) x[j] = sp_stable(a[j]);

  // ---- x path: 3 iterations of 5-branch blocks
  for (int i = 0; i < 3; ++i) {
    matvec<15>(w + OFF_XWS + i * 225, w + OFF_XLB + i * 15, x, a);
    matvec_acc<16>(w + OFF_XSW + i * 240, x0v, a);
    matvec_acc<15>(w + OFF_XYW + i * 225, y, a);
    matvec_acc<15>(w + OFF_XZW + i * 225, z, a);
    matvec_acc<15>(w + OFF_XTW + i * 225, t, a);
#pragma unroll
    for (int j = 0; j < HID; ++j) x[j] = sp_stable(a[j]);
  }

  // ---- final linear
  matvec<15>(w + OFF_FW, w + OFF_FB, x, a);

  float* orow = outg + (size_t)r * HID;
#pragma unroll
  for (int j = 0; j < HID; ++j) orow[j] = a[j];
}

extern "C" void kernel_launch(void* const* d_in, const int* in_sizes, int n_in,
                              void* d_out, int out_size, void* d_ws, size_t ws_size,
                              hipStream_t stream) {
  const float* x0  = (const float*)d_in[0];
  const float* y0  = (const float*)d_in[1];
  const float* z0  = (const float*)d_in[2];
  const float* t0  = (const float*)d_in[3];
  const float* yW0 = (const float*)d_in[4];
  const float* yWs = (const float*)d_in[5];
  const float* yb  = (const float*)d_in[6];
  const float* zW0 = (const float*)d_in[7];
  const float* zWs = (const float*)d_in[8];
  const float* zb  = (const float*)d_in[9];
  const float* tW0 = (const float*)d_in[10];
  const float* tWs = (const float*)d_in[11];
  const float* tb  = (const float*)d_in[12];
  const float* x0W = (const float*)d_in[13];
  const float* x0b = (const float*)d_in[14];
  const float* y0W = (const float*)d_in[15];
  const float* y0b = (const float*)d_in[16];
  const float* z0W = (const float*)d_in[17];
  const float* z0b = (const float*)d_in[18];
  const float* t0W = (const float*)d_in[19];
  const float* t0b = (const float*)d_in[20];
  const float* xWs = (const float*)d_in[21];
  const float* xb  = (const float*)d_in[22];
  const float* xsW = (const float*)d_in[23];
  const float* xsb = (const float*)d_in[24];
  const float* xyW = (const float*)d_in[25];
  const float* xyb = (const float*)d_in[26];
  const float* xzW = (const float*)d_in[27];
  const float* xzb = (const float*)d_in[28];
  const float* xtW = (const float*)d_in[29];
  const float* xtb = (const float*)d_in[30];
  const float* fW  = (const float*)d_in[31];
  const float* fb  = (const float*)d_in[32];

  float* w = (float*)d_ws;

  prep_kernel<<<4, 256, 0, stream>>>(yW0, yWs, yb, zW0, zWs, zb, tW0, tWs, tb,
                                     x0W, x0b, y0W, y0b, z0W, z0b, t0W, t0b,
                                     xWs, xb, xsW, xsb, xyW, xyb, xzW, xzb,
                                     xtW, xtb, fW, fb, w);

  const int n = in_sizes[0] / 16;  // N rows
  const int blocks = (n + 255) / 256;
  isnn_fwd<<<blocks, 256, 0, stream>>>(x0, y0, z0, t0, w, (float*)d_out, n);
}

// Round 3
// 273.554 us; speedup vs baseline: 1.0373x; 1.0373x over previous
//
#include <hip/hip_runtime.h>

typedef float f2 __attribute__((ext_vector_type(2)));

// ---- prepared weight buffer layout (float offsets in d_ws) ----
// All matrices stored TRANSPOSED + padded: wT[k][16], wT[k][j] = f(W[j][k]), j=15 -> 0
constexpr int OFF_YW0 = 0;       // IN=8   128  softplus'ed
constexpr int OFF_YWS = 128;     // 3x15x16 720 softplus'ed
constexpr int OFF_ZW0 = 848;     // 128
constexpr int OFF_ZWS = 976;     // 720
constexpr int OFF_TW0 = 1696;    // IN=4    64  softplus'ed
constexpr int OFF_TWS = 1760;    // 720  softplus'ed
constexpr int OFF_X0W = 2480;    // IN=16  256
constexpr int OFF_Y0W = 2736;    // 128  softplus'ed
constexpr int OFF_Z0W = 2864;    // 128
constexpr int OFF_T0W = 2992;    //  64  softplus'ed
constexpr int OFF_XWS = 3056;    // 720  softplus'ed
constexpr int OFF_XSW = 3776;    // 3x16x16 768
constexpr int OFF_XYW = 4544;    // 720  softplus'ed
constexpr int OFF_XZW = 5264;    // 720
constexpr int OFF_XTW = 5984;    // 720  softplus'ed
constexpr int OFF_FW  = 6704;    // 240
constexpr int OFF_YB  = 6944;    // 4x16 padded
constexpr int OFF_ZB  = 7008;    // 64
constexpr int OFF_TB  = 7072;    // 64
constexpr int OFF_XFB = 7136;    // 16 (x0b+y0b+z0b+t0b)
constexpr int OFF_XLB = 7152;    // 3x16 (xb+xsb+xyb+xzb+xtb per iter)
constexpr int OFF_FB  = 7200;    // 16
constexpr int W_TOTAL = 7216;

__device__ __forceinline__ float sp_stable(float v) {
  float ax = __builtin_fabsf(v);
  float e  = __expf(-ax);
  return fmaxf(v, 0.0f) + __logf(1.0f + e);
}

__device__ __forceinline__ float sigmoid_f(float v) {
  return __builtin_amdgcn_rcpf(1.0f + __expf(-v));
}

// ---------------- weight prep: transpose + pad + (optional) softplus -------------
// W layout (NL,15,IN) row-major -> dst[l*IN*16 + k*16 + j] = f(W[l][j][k]), j=15 pad 0
#define TPOSE(DST, SRC, IN, NL, SP)                                              \
  for (int i = tid; i < (NL) * (IN) * 16; i += str) {                            \
    int l = i / ((IN) * 16);                                                     \
    int rem = i - l * (IN) * 16;                                                 \
    int k = rem >> 4, j = rem & 15;                                              \
    float v = (j < 15) ? SRC[(l * 15 + j) * (IN) + k] : 0.0f;                    \
    w[(DST) + i] = ((SP) && j < 15) ? sp_stable(v) : v;                          \
  }

__global__ void prep_kernel(
    const float* __restrict__ yW0, const float* __restrict__ yWs, const float* __restrict__ yb,
    const float* __restrict__ zW0, const float* __restrict__ zWs, const float* __restrict__ zb,
    const float* __restrict__ tW0, const float* __restrict__ tWs, const float* __restrict__ tb,
    const float* __restrict__ x0W, const float* __restrict__ x0b,
    const float* __restrict__ y0W, const float* __restrict__ y0b,
    const float* __restrict__ z0W, const float* __restrict__ z0b,
    const float* __restrict__ t0W, const float* __restrict__ t0b,
    const float* __restrict__ xWs, const float* __restrict__ xb,
    const float* __restrict__ xsW, const float* __restrict__ xsb,
    const float* __restrict__ xyW, const float* __restrict__ xyb,
    const float* __restrict__ xzW, const float* __restrict__ xzb,
    const float* __restrict__ xtW, const float* __restrict__ xtb,
    const float* __restrict__ fW, const float* __restrict__ fb,
    float* __restrict__ w)
{
  const int tid = blockIdx.x * blockDim.x + threadIdx.x;
  const int str = gridDim.x * blockDim.x;
  TPOSE(OFF_YW0, yW0,  8, 1, 1)
  TPOSE(OFF_YWS, yWs, 15, 3, 1)
  TPOSE(OFF_ZW0, zW0,  8, 1, 0)
  TPOSE(OFF_ZWS, zWs, 15, 3, 0)
  TPOSE(OFF_TW0, tW0,  4, 1, 1)
  TPOSE(OFF_TWS, tWs, 15, 3, 1)
  TPOSE(OFF_X0W, x0W, 16, 1, 0)
  TPOSE(OFF_Y0W, y0W,  8, 1, 1)
  TPOSE(OFF_Z0W, z0W,  8, 1, 0)
  TPOSE(OFF_T0W, t0W,  4, 1, 1)
  TPOSE(OFF_XWS, xWs, 15, 3, 1)
  TPOSE(OFF_XSW, xsW, 16, 3, 0)
  TPOSE(OFF_XYW, xyW, 15, 3, 1)
  TPOSE(OFF_XZW, xzW, 15, 3, 0)
  TPOSE(OFF_XTW, xtW, 15, 3, 1)
  TPOSE(OFF_FW,  fW,  15, 1, 0)
  for (int i = tid; i < 64; i += str) { int l = i >> 4, j = i & 15;
    w[OFF_YB + i] = (j < 15) ? yb[l * 15 + j] : 0.0f; }
  for (int i = tid; i < 64; i += str) { int l = i >> 4, j = i & 15;
    w[OFF_ZB + i] = (j < 15) ? zb[l * 15 + j] : 0.0f; }
  for (int i = tid; i < 64; i += str) { int l = i >> 4, j = i & 15;
    w[OFF_TB + i] = (j < 15) ? tb[l * 15 + j] : 0.0f; }
  for (int i = tid; i < 16; i += str)
    w[OFF_XFB + i] = (i < 15) ? (x0b[i] + y0b[i] + z0b[i] + t0b[i]) : 0.0f;
  for (int i = tid; i < 48; i += str) { int l = i >> 4, j = i & 15;
    w[OFF_XLB + i] = (j < 15) ? (xb[l*15+j] + xsb[l*15+j] + xyb[l*15+j] + xzb[l*15+j] + xtb[l*15+j]) : 0.0f; }
  for (int i = tid; i < 16; i += str)
    w[OFF_FB + i] = (i < 15) ? fb[i] : 0.0f;
}

// ---------------- main kernel: one thread per row, f2-packed output channels ------
// acc[j2] covers output channels (2*j2, 2*j2+1); weights read as SGPR pairs;
// v_pk_fma_f32 does 2 FMAs per instruction.
template<int IN>
__device__ __forceinline__ void mv(const float* __restrict__ Wt,   // IN x 16
                                   const float* __restrict__ b16,  // 16 padded
                                   const float* __restrict__ in,
                                   f2* __restrict__ acc) {
  const f2* b2 = (const f2*)b16;
#pragma unroll
  for (int j2 = 0; j2 < 8; ++j2) acc[j2] = b2[j2];
#pragma unroll
  for (int k = 0; k < IN; ++k) {
    const f2* row = (const f2*)(Wt + k * 16);
    f2 inb = {in[k], in[k]};
#pragma unroll
    for (int j2 = 0; j2 < 8; ++j2)
      acc[j2] = __builtin_elementwise_fma(row[j2], inb, acc[j2]);
  }
}

template<int IN>
__device__ __forceinline__ void mv_acc(const float* __restrict__ Wt,
                                       const float* __restrict__ in,
                                       f2* __restrict__ acc) {
#pragma unroll
  for (int k = 0; k < IN; ++k) {
    const f2* row = (const f2*)(Wt + k * 16);
    f2 inb = {in[k], in[k]};
#pragma unroll
    for (int j2 = 0; j2 < 8; ++j2)
      acc[j2] = __builtin_elementwise_fma(row[j2], inb, acc[j2]);
  }
}

__global__ __launch_bounds__(256, 3) void isnn_fwd(
    const float* __restrict__ x0g, const float* __restrict__ y0g,
    const float* __restrict__ z0g, const float* __restrict__ t0g,
    const float* __restrict__ w,   float* __restrict__ outg, int n)
{
  const int r = blockIdx.x * blockDim.x + threadIdx.x;
  if (r >= n) return;

  float x0v[16], y0v[8], z0v[8], t0v[4];
#pragma unroll
  for (int k = 0; k < 4; ++k)
    ((float4*)x0v)[k] = ((const float4*)(x0g))[(size_t)r * 4 + k];
#pragma unroll
  for (int k = 0; k < 2; ++k)
    ((float4*)y0v)[k] = ((const float4*)(y0g))[(size_t)r * 2 + k];
#pragma unroll
  for (int k = 0; k < 2; ++k)
    ((float4*)z0v)[k] = ((const float4*)(z0g))[(size_t)r * 2 + k];
  ((float4*)t0v)[0] = ((const float4*)(t0g))[(size_t)r];

  float y[15], z[15], t[15], x[15];
  f2 a[8];

  // ---- y tower
  mv<8>(w + OFF_YW0, w + OFF_YB, y0v, a);
#pragma unroll
  for (int j = 0; j < 15; ++j) y[j] = sp_stable(((const float*)a)[j]);
  for (int i = 0; i < 3; ++i) {
    mv<15>(w + OFF_YWS + i * 240, w + OFF_YB + 16 + i * 16, y, a);
#pragma unroll
    for (int j = 0; j < 15; ++j) y[j] = sp_stable(((const float*)a)[j]);
  }

  // ---- z tower
  mv<8>(w + OFF_ZW0, w + OFF_ZB, z0v, a);
#pragma unroll
  for (int j = 0; j < 15; ++j) z[j] = sigmoid_f(((const float*)a)[j]);
  for (int i = 0; i < 3; ++i) {
    mv<15>(w + OFF_ZWS + i * 240, w + OFF_ZB + 16 + i * 16, z, a);
#pragma unroll
    for (int j = 0; j < 15; ++j) z[j] = sigmoid_f(((const float*)a)[j]);
  }

  // ---- t tower
  mv<4>(w + OFF_TW0, w + OFF_TB, t0v, a);
#pragma unroll
  for (int j = 0; j < 15; ++j) t[j] = sigmoid_f(((const float*)a)[j]);
  for (int i = 0; i < 3; ++i) {
    mv<15>(w + OFF_TWS + i * 240, w + OFF_TB + 16 + i * 16, t, a);
#pragma unroll
    for (int j = 0; j < 15; ++j) t[j] = sigmoid_f(((const float*)a)[j]);
  }

  // ---- x path: first 4-branch block
  mv<16>(w + OFF_X0W, w + OFF_XFB, x0v, a);
  mv_acc<8>(w + OFF_Y0W, y0v, a);
  mv_acc<8>(w + OFF_Z0W, z0v, a);
  mv_acc<4>(w + OFF_T0W, t0v, a);
#pragma unroll
  for (int j = 0; j < 15; ++j) x[j] = sp_stable(((const float*)a)[j]);

  // ---- x path: 3 iterations of 5-branch blocks
  for (int i = 0; i < 3; ++i) {
    mv<15>(w + OFF_XWS + i * 240, w + OFF_XLB + i * 16, x, a);
    mv_acc<16>(w + OFF_XSW + i * 256, x0v, a);
    mv_acc<15>(w + OFF_XYW + i * 240, y, a);
    mv_acc<15>(w + OFF_XZW + i * 240, z, a);
    mv_acc<15>(w + OFF_XTW + i * 240, t, a);
#pragma unroll
    for (int j = 0; j < 15; ++j) x[j] = sp_stable(((const float*)a)[j]);
  }

  // ---- final linear
  mv<15>(w + OFF_FW, w + OFF_FB, x, a);

  // ---- store 15 floats (4B-aligned vector stores)
  typedef float f4u __attribute__((ext_vector_type(4), aligned(4)));
  typedef float f2u __attribute__((ext_vector_type(2), aligned(4)));
  const float* af = (const float*)a;
  float* orow = outg + (size_t)r * 15;
  ((f4u*)orow)[0] = f4u{af[0], af[1], af[2], af[3]};
  ((f4u*)orow)[1] = f4u{af[4], af[5], af[6], af[7]};
  ((f4u*)orow)[2] = f4u{af[8], af[9], af[10], af[11]};
  *(f2u*)(orow + 12) = f2u{af[12], af[13]};
  orow[14] = af[14];
}

extern "C" void kernel_launch(void* const* d_in, const int* in_sizes, int n_in,
                              void* d_out, int out_size, void* d_ws, size_t ws_size,
                              hipStream_t stream) {
  const float* x0  = (const float*)d_in[0];
  const float* y0  = (const float*)d_in[1];
  const float* z0  = (const float*)d_in[2];
  const float* t0  = (const float*)d_in[3];
  const float* yW0 = (const float*)d_in[4];
  const float* yWs = (const float*)d_in[5];
  const float* yb  = (const float*)d_in[6];
  const float* zW0 = (const float*)d_in[7];
  const float* zWs = (const float*)d_in[8];
  const float* zb  = (const float*)d_in[9];
  const float* tW0 = (const float*)d_in[10];
  const float* tWs = (const float*)d_in[11];
  const float* tb  = (const float*)d_in[12];
  const float* x0W = (const float*)d_in[13];
  const float* x0b = (const float*)d_in[14];
  const float* y0W = (const float*)d_in[15];
  const float* y0b = (const float*)d_in[16];
  const float* z0W = (const float*)d_in[17];
  const float* z0b = (const float*)d_in[18];
  const float* t0W = (const float*)d_in[19];
  const float* t0b = (const float*)d_in[20];
  const float* xWs = (const float*)d_in[21];
  const float* xb  = (const float*)d_in[22];
  const float* xsW = (const float*)d_in[23];
  const float* xsb = (const float*)d_in[24];
  const float* xyW = (const float*)d_in[25];
  const float* xyb = (const float*)d_in[26];
  const float* xzW = (const float*)d_in[27];
  const float* xzb = (const float*)d_in[28];
  const float* xtW = (const float*)d_in[29];
  const float* xtb = (const float*)d_in[30];
  const float* fW  = (const float*)d_in[31];
  const float* fb  = (const float*)d_in[32];

  float* w = (float*)d_ws;

  prep_kernel<<<4, 256, 0, stream>>>(yW0, yWs, yb, zW0, zWs, zb, tW0, tWs, tb,
                                     x0W, x0b, y0W, y0b, z0W, z0b, t0W, t0b,
                                     xWs, xb, xsW, xsb, xyW, xyb, xzW, xzb,
                                     xtW, xtb, fW, fb, w);

  const int n = in_sizes[0] / 16;  // N rows
  const int blocks = (n + 255) / 256;
  isnn_fwd<<<blocks, 256, 0, stream>>>(x0, y0, z0, t0, w, (float*)d_out, n);
}